// Round 1
// baseline (267.669 us; speedup 1.0000x reference)
//
#include <hip/hip_runtime.h>

// CTC batch cost, linear-domain, single wave per batch element, DIAGONAL SKEW.
// Lane L owns states 4L..4L+3 (S=201) and at wave-step n computes time
// t = n - L. The left halo A[4L-1](t-1) is the left lane's a3 produced at
// wave-step n-2 -> each __shfl_up has 2 steps (~150cyc) of slack and leaves
// the critical path (round 2 had 2 serialized ~120cyc bpermutes per step).
//
// THIS ROUND: the 3 per-step ds_read_b32 prob gathers were consumed in the
// same step they were issued (compiler can't hoist them across the circular
// ds_write - can't prove ring-slot disjointness), putting the full ~120cyc
// LDS latency + ~11cyc bank-conflict serialization on the critical path
// every step (measured 286 cyc/step, VALUBusy 12%). Fix: register prefetch
// queue PQ[4] (compile-time indexed by unrolled j&3 -> stays in VGPRs),
// issuing the gathers 4 wave-steps ahead. Disjointness we know and the
// compiler doesn't: reads for step n+4 hit rows <= n+4; the write at step n
// hits row n+15 (slot distance 74 < 128); row r is written at step r-15 and
// read-issued at step r+lane-4 >= r-4 (>=11 steps later), recycled at step
// r+113 (>=49 steps after the read). Any prefetch depth <= 15 is safe.
//
// Probabilities: rows staged via a single-wave LDS circular buffer (128 slots
// x 130f padded stride): 1 coalesced float2 global load + 1 ds_write per step
// (8-deep VGPR queue, 15-step write->read distance), 3x ds_read_b32 consume.
// Single wave -> LDS ops are program-ordered; NO barrier in the loop.
//
// Recurrence (exactly round 2's, absmax 0.0):
//   n0 = (a0 + h1) * pb
//   n1 = (a1 + a0 + ms1*h1) * p_lab0
//   n2 = (a2 + a1) * pb
//   n3 = (a3 + a2 + ms3*a1) * p_lab1
// with per-lane exponent e (true alpha = a*2^e), renorm every 4 steps.

#define Bc 256
#define Tc 1024
#define Cc 128
#define Uc 100
#define BLANKc 127
#define EPSc 1e-7f
#define LN2f 0.69314718055994530942f
#define RSTRIDE 130          // floats per row slot (even -> 8B-aligned float2)
#define NSLOT 128            // circular buffer depth (needs >= 80 live rows)
#define QD 8                 // global->LDS staging queue depth
#define PF 4                 // prob-gather prefetch distance (wave-steps)

__global__ __launch_bounds__(64) void ctc_skew_kernel(
    const float* __restrict__ y_pred,     // [B,T,C] post-softmax probs
    const int*   __restrict__ y_true,     // [B,U]
    const int*   __restrict__ label_len,  // [B]
    float*       __restrict__ out)        // [B,1]
{
    __shared__ float rowbuf[NSLOT * RSTRIDE];   // 66560 B circular row cache
    __shared__ float shA[204];
    __shared__ int   shE[64];

    const int b    = blockIdx.x;
    const int lane = threadIdx.x;                  // 0..63
    const float* gp = y_pred + (size_t)b * (Tc * Cc);

    // ---- per-lane label classes & skip masks (time-invariant) ----
    const int k0  = 2*lane, k1 = 2*lane+1;
    const int k0c = k0 < Uc ? k0 : Uc-1;
    const int k1c = k1 < Uc ? k1 : Uc-1;
    const int y0  = y_true[b*Uc + k0c];            // class of state 4L+1
    const int y1  = y_true[b*Uc + k1c];            // class of state 4L+3
    int ym1 = y0;
    if (lane > 0) ym1 = y_true[b*Uc + k0 - 1];
    const float ms1 = (lane > 0 && y0 != ym1) ? 1.0f : 0.0f;
    const float ms3 = (y1 != y0) ? 1.0f : 0.0f;
    const float mh  = (lane > 0) ? 1.0f : 0.0f;    // lane 0 has no left halo

    // ---- t=0 init (only lane 0 holds mass) ----
    float a0=0.f, a1=0.f, a2=0.f, a3=0.f;
    if (lane == 0) { a0 = gp[BLANKc]+EPSc; a1 = gp[y0]+EPSc; }
    int e = 0;

    // ---- pre-stage rows 0..15 into LDS (coalesced float4 reads) ----
#pragma unroll
    for (int i = 0; i < 8; ++i) {
        const int f4  = i*64 + lane;               // 512 float4 across 16 rows
        const int row = f4 >> 5;                   // 32 float4 per row
        const int c4  = (f4 & 31) * 4;
        const float4 v = *(const float4*)(gp + row*Cc + c4);
        float* dst = &rowbuf[row*RSTRIDE + c4];
        dst[0]=v.x; dst[1]=v.y; dst[2]=v.z; dst[3]=v.w;
    }
    // single wave: LDS writes/reads are program-ordered; no barrier needed.

    // ---- staging queue: rows 16..23 in flight ----
    float2 Q[QD];
#pragma unroll
    for (int k = 0; k < QD; ++k)
        Q[k] = *(const float2*)(gp + (16+k)*Cc + lane*2);

    // ---- prob-gather prefetch queue: PQ[k] holds step n=k+1's values ----
    float PQb[PF], PQ0[PF], PQ1[PF];
#pragma unroll
    for (int k = 0; k < PF; ++k) {
        int rr = (k+1) - lane; rr = rr < 0 ? 0 : rr;
        const float* rowp = &rowbuf[(rr & (NSLOT-1)) * RSTRIDE];
        PQb[k] = rowp[BLANKc]; PQ0[k] = rowp[y0]; PQ1[k] = rowp[y1];
    }

    // ---- halo queue (2-step shuffle latency); initial a3=0, e=0 everywhere
    float q2a = 0.f, q1a = 0.f;
    int   q2e = 0,   q1e = 0;

    auto body = [&](int n, int j, bool fzp) {
        // -- consume this step's probs (gathered PF steps ago, latency gone)
        const int qi = j & (PF-1);                 // == (n-1)&3: base n==16c+1
        const float pbr = PQb[qi];
        const float p0r = PQ0[qi];
        const float p1r = PQ1[qi];
        // -- refill slot with step n+PF's gathers (rows <= n+PF: written
        //    >=11 steps ago, slot-disjoint from this step's ds_write) --
        int rr4 = n + PF - lane; rr4 = rr4 < 0 ? 0 : rr4;
        const float* rp4 = &rowbuf[(rr4 & (NSLOT-1)) * RSTRIDE];
        PQb[qi] = rp4[BLANKc]; PQ0[qi] = rp4[y0]; PQ1[qi] = rp4[y1];
        // -- stage: ds_write row n+15 (loaded 8 steps ago), reload row n+23 --
        const int j8 = (n-1) & (QD-1);
        const int ws = (n+15) & (NSLOT-1);
        *(float2*)&rowbuf[ws*RSTRIDE + lane*2] = Q[j8];
        int lr = n+23; lr = lr > Tc-1 ? Tc-1 : lr;
        Q[j8] = *(const float2*)(gp + lr*Cc + lane*2);
        // -- halo issued 2 wave-steps ago = left's state after its t-1 --
        const float h1r = q2a; const int el = q2e;
        q2a = q1a; q2e = q1e;
        int d = el - e; d = d > 126 ? 126 : d;     // clamp: avoid inf blowup
        const float h1 = mh * ldexpf(h1r, d);
        const float pb = pbr + EPSc, p0 = p0r + EPSc, p1 = p1r + EPSc;
        const float n0 = (a0 + h1) * pb;
        const float n1 = (a1 + a0 + ms1*h1) * p0;
        const float n2 = (a2 + a1) * pb;
        const float n3 = (a3 + a2 + ms3*a1) * p1;
        const float sm = (n0+n1)+(n2+n3);
        const int   en = (sm > 0.0f) ? e : el;     // dormant lanes track left e
        bool upd = true;
        if (fzp) upd = (lane >= n - (Tc-1));       // freeze lanes past t=1023
        if (upd) { a0=n0; a1=n1; a2=n2; a3=n3; e=en; }
        if ((j & 3) == 3) {                        // renorm (preserves a*2^e)
            const float m = fmaxf(fmaxf(a0,a1), fmaxf(a2,a3));
            int ex = (int)((__float_as_uint(m) >> 23) & 0xFF) - 127;
            ex = (m > 0.0f) ? ex : 0;
            a0 = ldexpf(a0,-ex); a1 = ldexpf(a1,-ex);
            a2 = ldexpf(a2,-ex); a3 = ldexpf(a3,-ex);
            e += ex;
        }
        // -- issue halo for wave-step n+2 (a3,e pair post-renorm: consistent)
        q1a = __shfl_up(a3, 1, 64);
        q1e = __shfl_up(e , 1, 64);
    };

    // ---- wave-steps n = 1..1086 (= 1023 times + 63 drain) ----
    int n = 1;
    for (int c = 0; c < 63; ++c) {                 // n = 1..1008: no freeze
#pragma unroll
        for (int j = 0; j < 16; ++j) { body(n, j, false); ++n; }
    }
    for (int c = 0; c < 4; ++c) {                  // n = 1009..1072 (freeze
#pragma unroll                                     //  predicate inert <1024)
        for (int j = 0; j < 16; ++j) { body(n, j, true); ++n; }
    }
#pragma unroll
    for (int j = 0; j < 14; ++j) { body(n, j, true); ++n; }  // n = 1073..1086

    // ---- epilogue: loss = -ln( A[2L-1] + A[2L] ), A = a * 2^e ----
    if (lane < 51) {
        shA[4*lane+0] = a0; shA[4*lane+1] = a1;
        shA[4*lane+2] = a2; shA[4*lane+3] = a3;
        shE[lane] = e;
    }
    __syncthreads();                               // one-time, post-loop
    if (lane == 0) {
        const int L  = label_len[b];
        const int s1 = 2*L - 1, s2 = 2*L;
        const float v1 = shA[s1], v2 = shA[s2];
        const int   e1 = shE[s1 >> 2], e2 = shE[s2 >> 2];
        const int   em = e1 > e2 ? e1 : e2;
        const float sum = ldexpf(v1, e1-em) + ldexpf(v2, e2-em);
        const float r   = __log2f(sum) + (float)em;
        out[b] = -LN2f * r;
    }
}

extern "C" void kernel_launch(void* const* d_in, const int* in_sizes, int n_in,
                              void* d_out, int out_size, void* d_ws, size_t ws_size,
                              hipStream_t stream) {
    const float* y_pred    = (const float*)d_in[0];
    const int*   y_true    = (const int*)d_in[1];
    const int*   label_len = (const int*)d_in[2];
    float*       out       = (float*)d_out;
    ctc_skew_kernel<<<Bc, 64, 0, stream>>>(y_pred, y_true, label_len, out);
}